// Round 3
// baseline (1618.040 us; speedup 1.0000x reference)
//
#include <hip/hip_runtime.h>
#include <math.h>

// GCN: 2x GraphConv(norm='both') + projection + softmax.
// N=100000 nodes, E=1600000 edges, feats 128 -> 64 -> 64 -> 8. All fp32.
//
// R2 rewrite: exact-CSR fill (random 4B scatter, 105 MB writebacks, 129 us)
// replaced by coarse counting-sort into 128-node dst buckets (contiguous runs,
// ~6.4 MB payload) + bucket aggregation with agg[128][64] in LDS (ds_add_f32).
// deg_in is computed locally per bucket; global scan + gather kernels removed.

#define NODES   100000
#define INF     128
#define HID     64
#define NLAB    8

#define BSHIFT  7                       // 128 nodes per bucket
#define BNODES  128
#define NB      ((NODES + BNODES - 1) / BNODES)   // 782
#define CAP     2600                    // bucket capacity (mean 2048, sigma 45)
#define CHUNK   8192                    // edges per group_kernel WG
#define SRCMASK 131071                  // 17 bits

// ---------------- group: bucket edges by dst>>7, count deg_out ----------------

__global__ void group_kernel(const int* __restrict__ src, const int* __restrict__ dst,
                             int* __restrict__ deg_o, int* __restrict__ gcur,
                             int* __restrict__ packed, int E) {
    __shared__ int hist[NB];
    __shared__ int base[NB];

    const int tid = threadIdx.x;
    const int e0 = blockIdx.x * CHUNK;

    for (int i = tid; i < NB; i += 256) hist[i] = 0;
    __syncthreads();

    // phase 1: histogram + deg_out
    for (int i = 0; i < CHUNK / 256; ++i) {
        int e = e0 + tid + i * 256;
        if (e < E) {
            atomicAdd(&deg_o[src[e]], 1);
            atomicAdd(&hist[dst[e] >> BSHIFT], 1);
        }
    }
    __syncthreads();

    // phase 2: reserve space per bucket (one far atomic per non-empty bucket)
    for (int b = tid; b < NB; b += 256) {
        int c = hist[b];
        base[b] = c ? atomicAdd(&gcur[b], c) : 0;
    }
    __syncthreads();
    for (int b = tid; b < NB; b += 256) hist[b] = 0;   // reuse as running rank
    __syncthreads();

    // phase 3: write packed (dst_local<<17 | src) into contiguous bucket runs
    for (int i = 0; i < CHUNK / 256; ++i) {
        int e = e0 + tid + i * 256;
        if (e < E) {
            int s = src[e], d = dst[e];
            int b = d >> BSHIFT;
            int pos = base[b] + atomicAdd(&hist[b], 1);
            if (pos < CAP)
                packed[(size_t)b * CAP + pos] = ((d & (BNODES - 1)) << 17) | s;
        }
    }
}

// ---------------- norm_src from deg_out ----------------

__global__ void norm_kernel(const int* __restrict__ deg_o, float* __restrict__ ns, int n) {
    int i = blockIdx.x * 256 + threadIdx.x;
    if (i < n) ns[i] = rsqrtf(fmaxf((float)deg_o[i], 1.0f));
}

// ---------------- GEMM: H[row,:] = norm[row] * (X[row,:] @ W) ----------------

template <int K>
__global__ void gemm_norm_kernel(const float* __restrict__ X, const float* __restrict__ norm,
                                 const float* __restrict__ W, float* __restrict__ H, int M) {
    constexpr int KS = K + 4;
    __shared__ float sW[K * 64];
    __shared__ float sX[16 * KS];

    const int tid = threadIdx.x;
    const int row0 = blockIdx.x * 16;

    for (int i = tid; i < K * 16; i += 256)
        ((float4*)sW)[i] = ((const float4*)W)[i];
    for (int i = tid; i < 4 * K; i += 256) {
        int eo = i * 4;
        int r = eo / K, k = eo % K;
        int gr = row0 + r;
        float4 v = (gr < M) ? ((const float4*)(X + (size_t)gr * K))[k >> 2]
                            : make_float4(0.f, 0.f, 0.f, 0.f);
        ((float4*)(sX + r * KS))[k >> 2] = v;
    }
    __syncthreads();

    const int c4 = tid & 15;
    const int r  = tid >> 4;
    const int grow = row0 + r;
    const float* xr = sX + r * KS;

    float4 acc = make_float4(0.f, 0.f, 0.f, 0.f);
#pragma unroll 8
    for (int k = 0; k < K; ++k) {
        float xv = xr[k];
        float4 w = ((const float4*)(sW + k * 64))[c4];
        acc.x = fmaf(xv, w.x, acc.x);
        acc.y = fmaf(xv, w.y, acc.y);
        acc.z = fmaf(xv, w.z, acc.z);
        acc.w = fmaf(xv, w.w, acc.w);
    }
    if (grow < M) {
        float nm = norm[grow];
        acc.x *= nm; acc.y *= nm; acc.z *= nm; acc.w *= nm;
        ((float4*)(H + (size_t)grow * 64))[c4] = acc;
    }
}

// ---------------- bucket aggregation + fused epilogue ----------------
// WG b owns dst nodes [b*128, b*128+128). agg[128][64] in LDS (32 KB).
// Per edge: wave reads h[src,:] coalesced (1 float/lane), ds_add_f32 into agg.
// deg_in counted locally. Epilogue: x = relu(rsqrt(deg)*agg + bias).

__global__ void __launch_bounds__(256, 4)
bucket_agg_kernel(const int* __restrict__ packed, const int* __restrict__ gcur,
                  const float* __restrict__ H, const float* __restrict__ bias,
                  float* __restrict__ X, int Nn) {
    __shared__ float agg[BNODES * 64];
    __shared__ int ldeg[BNODES];

    const int tid = threadIdx.x;
    const int lane = tid & 63;
    const int w = tid >> 6;                 // wave 0..3
    const int b = blockIdx.x;
    const int node0 = b * BNODES;

    for (int i = tid; i < BNODES * 64; i += 256) agg[i] = 0.f;
    for (int i = tid; i < BNODES; i += 256) ldeg[i] = 0;
    const float bl = bias[lane];
    __syncthreads();

    const int cnt = min(gcur[b], CAP);
    const int* reg = packed + (size_t)b * CAP;

    for (int bse = w * 64; bse < cnt; bse += 256) {
        int idx = bse + lane;
        int pe = (idx < cnt) ? reg[idx] : 0;
        if (idx < cnt) atomicAdd(&ldeg[pe >> 17], 1);
        int nv = min(cnt - bse, 64);
        int j = 0;
        for (; j + 3 < nv; j += 4) {
            int e0 = __builtin_amdgcn_readlane(pe, j);
            int e1 = __builtin_amdgcn_readlane(pe, j + 1);
            int e2 = __builtin_amdgcn_readlane(pe, j + 2);
            int e3 = __builtin_amdgcn_readlane(pe, j + 3);
            float v0 = H[(size_t)(e0 & SRCMASK) * 64 + lane];
            float v1 = H[(size_t)(e1 & SRCMASK) * 64 + lane];
            float v2 = H[(size_t)(e2 & SRCMASK) * 64 + lane];
            float v3 = H[(size_t)(e3 & SRCMASK) * 64 + lane];
            atomicAdd(&agg[(e0 >> 17) * 64 + lane], v0);
            atomicAdd(&agg[(e1 >> 17) * 64 + lane], v1);
            atomicAdd(&agg[(e2 >> 17) * 64 + lane], v2);
            atomicAdd(&agg[(e3 >> 17) * 64 + lane], v3);
        }
        for (; j < nv; ++j) {
            int e = __builtin_amdgcn_readlane(pe, j);
            float v = H[(size_t)(e & SRCMASK) * 64 + lane];
            atomicAdd(&agg[(e >> 17) * 64 + lane], v);
        }
    }
    __syncthreads();

    for (int r = w; r < BNODES; r += 4) {
        int node = node0 + r;
        if (node >= Nn) break;
        float nd = rsqrtf(fmaxf((float)ldeg[r], 1.0f));
        float v = fmaf(agg[r * 64 + lane], nd, bl);
        X[(size_t)node * 64 + lane] = fmaxf(v, 0.f);
    }
}

// ---------------- projection (64x8) + softmax ----------------

__global__ void proj_softmax_kernel(const float* __restrict__ X, const float* __restrict__ Wp,
                                    const float* __restrict__ bp, float* __restrict__ out, int M) {
    __shared__ float sW[64 * NLAB];
    __shared__ float sb[NLAB];
    int tid = threadIdx.x;
    for (int i = tid; i < 64 * NLAB; i += 256) sW[i] = Wp[i];
    if (tid < NLAB) sb[tid] = bp[tid];
    __syncthreads();

    int row = blockIdx.x * 256 + tid;
    if (row >= M) return;

    float logit[NLAB];
#pragma unroll
    for (int l = 0; l < NLAB; ++l) logit[l] = sb[l];
    const float4* x4 = (const float4*)(X + (size_t)row * 64);
#pragma unroll 4
    for (int kk = 0; kk < 16; ++kk) {
        float4 v = x4[kk];
        const float xs[4] = {v.x, v.y, v.z, v.w};
#pragma unroll
        for (int j = 0; j < 4; ++j) {
            int k = kk * 4 + j;
            float xv = xs[j];
#pragma unroll
            for (int l = 0; l < NLAB; ++l)
                logit[l] = fmaf(xv, sW[k * NLAB + l], logit[l]);
        }
    }
    float mx = logit[0];
#pragma unroll
    for (int l = 1; l < NLAB; ++l) mx = fmaxf(mx, logit[l]);
    float s = 0.0f;
#pragma unroll
    for (int l = 0; l < NLAB; ++l) { logit[l] = __expf(logit[l] - mx); s += logit[l]; }
    float inv = 1.0f / s;
#pragma unroll
    for (int l = 0; l < NLAB; ++l) out[(size_t)row * NLAB + l] = logit[l] * inv;
}

// ---------------- launch ----------------

extern "C" void kernel_launch(void* const* d_in, const int* in_sizes, int n_in,
                              void* d_out, int out_size, void* d_ws, size_t ws_size,
                              hipStream_t stream) {
    const float* features = (const float*)d_in[0];
    const int*   edge_src = (const int*)d_in[1];
    const int*   edge_dst = (const int*)d_in[2];
    const float* W1 = (const float*)d_in[4];
    const float* b1 = (const float*)d_in[5];
    const float* W2 = (const float*)d_in[6];
    const float* b2 = (const float*)d_in[7];
    const float* Wp = (const float*)d_in[8];
    const float* bp = (const float*)d_in[9];
    float* out = (float*)d_out;

    const int N = NODES;
    const int E = in_sizes[1];

    // ---- workspace layout (~60.2 MB) ----
    char* p = (char*)d_ws;
    int*   deg_o  = (int*)p;            p += sizeof(int) * N;          // zeroed
    int*   gcur   = (int*)p;            p += sizeof(int) * NB;         // zeroed
    int*   packed = (int*)p;            p += sizeof(int) * (size_t)NB * CAP;
    float* norm_s = (float*)p;          p += sizeof(float) * N;
    p = (char*)(((size_t)p + 255) & ~(size_t)255);
    float* h      = (float*)p;          p += sizeof(float) * (size_t)N * 64;
    float* x      = (float*)p;          p += sizeof(float) * (size_t)N * 64;

    hipMemsetAsync(deg_o, 0, sizeof(int) * ((size_t)N + NB), stream);  // deg_o + gcur

    // ---- bucket the edges (replaces deg/scan/fill) ----
    group_kernel<<<(E + CHUNK - 1) / CHUNK, 256, 0, stream>>>(edge_src, edge_dst,
                                                              deg_o, gcur, packed, E);
    norm_kernel<<<(N + 255) / 256, 256, 0, stream>>>(deg_o, norm_s, N);

    // ---- layer 1 ----
    gemm_norm_kernel<INF><<<(N + 15) / 16, 256, 0, stream>>>(features, norm_s, W1, h, N);
    bucket_agg_kernel<<<NB, 256, 0, stream>>>(packed, gcur, h, b1, x, N);

    // ---- layer 2 ----
    gemm_norm_kernel<HID><<<(N + 15) / 16, 256, 0, stream>>>(x, norm_s, W2, h, N);
    bucket_agg_kernel<<<NB, 256, 0, stream>>>(packed, gcur, h, b2, x, N);

    // ---- projection + softmax ----
    proj_softmax_kernel<<<(N + 255) / 256, 256, 0, stream>>>(x, Wp, bp, out, N);
}

// Round 4
// 406.789 us; speedup vs baseline: 3.9776x; 3.9776x over previous
//
#include <hip/hip_runtime.h>
#include <math.h>

// GCN: 2x GraphConv(norm='both') + projection + softmax.
// N=100000 nodes, E=1600000 edges, feats 128 -> 64 -> 64 -> 8. All fp32.
//
// R3 post-mortem: LDS bucket-aggregation was latency-bound (782 WGs, 21% occ,
// readlane-serialized edges). Reverted to R1's wave-per-node gather (0 LDS,
// 25k WGs, 4 loads in flight). Kept R3's coarse bucketing (contiguous writes)
// and added an in-LDS per-bucket counting sort -> exact CSR, replacing R1's
// random-scatter fill_kernel (105 MB writebacks) and all global dst atomics.

#define NODES   100000
#define INF     128
#define HID     64
#define NLAB    8

#define BSHIFT  7                       // 128 nodes per bucket
#define BNODES  128
#define NB      ((NODES + BNODES - 1) / BNODES)   // 782
#define CAP     2600                    // bucket capacity (mean 2046, ~12 sigma)
#define CHUNK   8192                    // edges per group_kernel WG
#define SRCMASK 131071                  // 17 bits

// ---------------- group: bucket edges by dst>>7, count deg_out ----------------

__global__ void group_kernel(const int* __restrict__ src, const int* __restrict__ dst,
                             int* __restrict__ deg_o, int* __restrict__ gcur,
                             int* __restrict__ packed, int E) {
    __shared__ int hist[NB];
    __shared__ int base[NB];

    const int tid = threadIdx.x;
    const int e0 = blockIdx.x * CHUNK;

    for (int i = tid; i < NB; i += 256) hist[i] = 0;
    __syncthreads();

    // phase 1: histogram + deg_out
    for (int i = 0; i < CHUNK / 256; ++i) {
        int e = e0 + tid + i * 256;
        if (e < E) {
            atomicAdd(&deg_o[src[e]], 1);
            atomicAdd(&hist[dst[e] >> BSHIFT], 1);
        }
    }
    __syncthreads();

    // phase 2: reserve space per bucket (one far atomic per non-empty bucket)
    for (int b = tid; b < NB; b += 256) {
        int c = hist[b];
        base[b] = c ? atomicAdd(&gcur[b], c) : 0;
    }
    __syncthreads();
    for (int b = tid; b < NB; b += 256) hist[b] = 0;   // reuse as running rank
    __syncthreads();

    // phase 3: write packed (dst_local<<17 | src) into contiguous bucket runs
    for (int i = 0; i < CHUNK / 256; ++i) {
        int e = e0 + tid + i * 256;
        if (e < E) {
            int s = src[e], d = dst[e];
            int b = d >> BSHIFT;
            int pos = base[b] + atomicAdd(&hist[b], 1);
            if (pos < CAP)
                packed[(size_t)b * CAP + pos] = ((d & (BNODES - 1)) << 17) | s;
        }
    }
}

// ---------------- norm_src from deg_out ----------------

__global__ void norm_kernel(const int* __restrict__ deg_o, float* __restrict__ ns, int n) {
    int i = blockIdx.x * 256 + threadIdx.x;
    if (i < n) ns[i] = rsqrtf(fmaxf((float)deg_o[i], 1.0f));
}

// ---------------- per-bucket counting sort -> exact CSR (in place) ----------------
// WG b: stage packed[b] in LDS, histogram 128 local dsts, scan, rank-scatter in
// LDS, write dst-sorted src ids back over packed[b]. Emits starts/ends/norm_d.

__global__ void local_csr_kernel(int* __restrict__ packed, const int* __restrict__ gcur,
                                 int* __restrict__ starts, int* __restrict__ ends,
                                 float* __restrict__ norm_d, int Nn) {
    __shared__ int raw[CAP];
    __shared__ int sorted[CAP];
    __shared__ int hist[BNODES];
    __shared__ int excl[BNODES];

    const int tid = threadIdx.x;
    const int b = blockIdx.x;
    const int cnt = min(gcur[b], CAP);
    int* reg = packed + (size_t)b * CAP;

    for (int i = tid; i < BNODES; i += 256) hist[i] = 0;
    __syncthreads();

    for (int i = tid; i < cnt; i += 256) {
        int pe = reg[i];
        raw[i] = pe;
        atomicAdd(&hist[pe >> 17], 1);
    }
    __syncthreads();

    // exclusive scan of 128 degrees (Hillis-Steele, first 128 threads)
    if (tid < BNODES) excl[tid] = hist[tid];
    __syncthreads();
    for (int off = 1; off < BNODES; off <<= 1) {
        int v = 0;
        if (tid < BNODES && tid >= off) v = excl[tid - off];
        __syncthreads();
        if (tid < BNODES) excl[tid] += v;
        __syncthreads();
    }
    if (tid < BNODES) {
        int deg = hist[tid];
        int st = excl[tid] - deg;               // exclusive
        excl[tid] = st;
        int node = b * BNODES + tid;
        if (node < Nn) {
            int gs = b * CAP + st;
            starts[node] = gs;
            ends[node]   = gs + deg;
            norm_d[node] = rsqrtf(fmaxf((float)deg, 1.0f));
        }
        hist[tid] = st;                          // reuse as cursor
    }
    __syncthreads();

    // rank scatter into sorted[]
    for (int i = tid; i < cnt; i += 256) {
        int pe = raw[i];
        int pos = atomicAdd(&hist[pe >> 17], 1);
        sorted[pos] = pe & SRCMASK;
    }
    __syncthreads();

    // coalesced write-back over the packed region
    for (int i = tid; i < cnt; i += 256) reg[i] = sorted[i];
}

// ---------------- GEMM: H[row,:] = norm[row] * (X[row,:] @ W) ----------------

template <int K>
__global__ void gemm_norm_kernel(const float* __restrict__ X, const float* __restrict__ norm,
                                 const float* __restrict__ W, float* __restrict__ H, int M) {
    constexpr int KS = K + 4;
    __shared__ float sW[K * 64];
    __shared__ float sX[16 * KS];

    const int tid = threadIdx.x;
    const int row0 = blockIdx.x * 16;

    for (int i = tid; i < K * 16; i += 256)
        ((float4*)sW)[i] = ((const float4*)W)[i];
    for (int i = tid; i < 4 * K; i += 256) {
        int eo = i * 4;
        int r = eo / K, k = eo % K;
        int gr = row0 + r;
        float4 v = (gr < M) ? ((const float4*)(X + (size_t)gr * K))[k >> 2]
                            : make_float4(0.f, 0.f, 0.f, 0.f);
        ((float4*)(sX + r * KS))[k >> 2] = v;
    }
    __syncthreads();

    const int c4 = tid & 15;
    const int r  = tid >> 4;
    const int grow = row0 + r;
    const float* xr = sX + r * KS;

    float4 acc = make_float4(0.f, 0.f, 0.f, 0.f);
#pragma unroll 8
    for (int k = 0; k < K; ++k) {
        float xv = xr[k];
        float4 w = ((const float4*)(sW + k * 64))[c4];
        acc.x = fmaf(xv, w.x, acc.x);
        acc.y = fmaf(xv, w.y, acc.y);
        acc.z = fmaf(xv, w.z, acc.z);
        acc.w = fmaf(xv, w.w, acc.w);
    }
    if (grow < M) {
        float nm = norm[grow];
        acc.x *= nm; acc.y *= nm; acc.z *= nm; acc.w *= nm;
        ((float4*)(H + (size_t)grow * 64))[c4] = acc;
    }
}

// ---------------- pull gather + fused epilogue (R1 design) ----------------
// One wave per dst node. Quarter q handles edges i = start+q, start+q+4, ...;
// lane-in-quarter c reads float4 cols 4c..4c+3. Cross-quarter shfl reduce.
// X[n,:] = relu(norm_d[n] * sum_{s in csr(n)} H[s,:] + b)

__global__ void gather_kernel(const int* __restrict__ starts, const int* __restrict__ ends,
                              const int* __restrict__ csr, const float* __restrict__ H,
                              const float* __restrict__ nd, const float* __restrict__ b,
                              float* __restrict__ X, int Nn) {
    int node = blockIdx.x * 4 + (threadIdx.x >> 6);
    if (node >= Nn) return;                     // wave-uniform
    int lane = threadIdx.x & 63;
    int q = lane >> 4, c = lane & 15;

    int start = starts[node], end = ends[node];
    float4 acc = make_float4(0.f, 0.f, 0.f, 0.f);
    for (int i = start + q; i < end; i += 4) {
        int s = csr[i];
        float4 v = ((const float4*)(H + (size_t)s * 64))[c];
        acc.x += v.x; acc.y += v.y; acc.z += v.z; acc.w += v.w;
    }
#pragma unroll
    for (int m = 16; m <= 32; m <<= 1) {
        acc.x += __shfl_xor(acc.x, m, 64);
        acc.y += __shfl_xor(acc.y, m, 64);
        acc.z += __shfl_xor(acc.z, m, 64);
        acc.w += __shfl_xor(acc.w, m, 64);
    }
    if (q == 0) {
        float nm = nd[node];
        float4 bb = ((const float4*)b)[c];
        float4 r;
        r.x = fmaxf(fmaf(acc.x, nm, bb.x), 0.f);
        r.y = fmaxf(fmaf(acc.y, nm, bb.y), 0.f);
        r.z = fmaxf(fmaf(acc.z, nm, bb.z), 0.f);
        r.w = fmaxf(fmaf(acc.w, nm, bb.w), 0.f);
        ((float4*)(X + (size_t)node * 64))[c] = r;
    }
}

// ---------------- projection (64x8) + softmax ----------------

__global__ void proj_softmax_kernel(const float* __restrict__ X, const float* __restrict__ Wp,
                                    const float* __restrict__ bp, float* __restrict__ out, int M) {
    __shared__ float sW[64 * NLAB];
    __shared__ float sb[NLAB];
    int tid = threadIdx.x;
    for (int i = tid; i < 64 * NLAB; i += 256) sW[i] = Wp[i];
    if (tid < NLAB) sb[tid] = bp[tid];
    __syncthreads();

    int row = blockIdx.x * 256 + tid;
    if (row >= M) return;

    float logit[NLAB];
#pragma unroll
    for (int l = 0; l < NLAB; ++l) logit[l] = sb[l];
    const float4* x4 = (const float4*)(X + (size_t)row * 64);
#pragma unroll 4
    for (int kk = 0; kk < 16; ++kk) {
        float4 v = x4[kk];
        const float xs[4] = {v.x, v.y, v.z, v.w};
#pragma unroll
        for (int j = 0; j < 4; ++j) {
            int k = kk * 4 + j;
            float xv = xs[j];
#pragma unroll
            for (int l = 0; l < NLAB; ++l)
                logit[l] = fmaf(xv, sW[k * NLAB + l], logit[l]);
        }
    }
    float mx = logit[0];
#pragma unroll
    for (int l = 1; l < NLAB; ++l) mx = fmaxf(mx, logit[l]);
    float s = 0.0f;
#pragma unroll
    for (int l = 0; l < NLAB; ++l) { logit[l] = __expf(logit[l] - mx); s += logit[l]; }
    float inv = 1.0f / s;
#pragma unroll
    for (int l = 0; l < NLAB; ++l) out[(size_t)row * NLAB + l] = logit[l] * inv;
}

// ---------------- launch ----------------

extern "C" void kernel_launch(void* const* d_in, const int* in_sizes, int n_in,
                              void* d_out, int out_size, void* d_ws, size_t ws_size,
                              hipStream_t stream) {
    const float* features = (const float*)d_in[0];
    const int*   edge_src = (const int*)d_in[1];
    const int*   edge_dst = (const int*)d_in[2];
    const float* W1 = (const float*)d_in[4];
    const float* b1 = (const float*)d_in[5];
    const float* W2 = (const float*)d_in[6];
    const float* b2 = (const float*)d_in[7];
    const float* Wp = (const float*)d_in[8];
    const float* bp = (const float*)d_in[9];
    float* out = (float*)d_out;

    const int N = NODES;
    const int E = in_sizes[1];

    // ---- workspace layout (~62 MB) ----
    char* p = (char*)d_ws;
    int*   deg_o  = (int*)p;            p += sizeof(int) * N;          // zeroed
    int*   gcur   = (int*)p;            p += sizeof(int) * NB;         // zeroed
    int*   packed = (int*)p;            p += sizeof(int) * (size_t)NB * CAP;  // -> csr
    int*   starts = (int*)p;            p += sizeof(int) * N;
    int*   ends   = (int*)p;            p += sizeof(int) * N;
    float* norm_s = (float*)p;          p += sizeof(float) * N;
    float* norm_d = (float*)p;          p += sizeof(float) * N;
    p = (char*)(((size_t)p + 255) & ~(size_t)255);
    float* h      = (float*)p;          p += sizeof(float) * (size_t)N * 64;
    float* x      = (float*)p;          p += sizeof(float) * (size_t)N * 64;

    hipMemsetAsync(deg_o, 0, sizeof(int) * ((size_t)N + NB), stream);  // deg_o + gcur

    // ---- CSR build: coarse bucket + in-LDS counting sort ----
    group_kernel<<<(E + CHUNK - 1) / CHUNK, 256, 0, stream>>>(edge_src, edge_dst,
                                                              deg_o, gcur, packed, E);
    local_csr_kernel<<<NB, 256, 0, stream>>>(packed, gcur, starts, ends, norm_d, N);
    norm_kernel<<<(N + 255) / 256, 256, 0, stream>>>(deg_o, norm_s, N);

    // ---- layer 1 ----
    gemm_norm_kernel<INF><<<(N + 15) / 16, 256, 0, stream>>>(features, norm_s, W1, h, N);
    gather_kernel<<<(N + 3) / 4, 256, 0, stream>>>(starts, ends, packed, h, norm_d, b1, x, N);

    // ---- layer 2 ----
    gemm_norm_kernel<HID><<<(N + 15) / 16, 256, 0, stream>>>(x, norm_s, W2, h, N);
    gather_kernel<<<(N + 3) / 4, 256, 0, stream>>>(starts, ends, packed, h, norm_d, b2, x, N);

    // ---- projection + softmax ----
    proj_softmax_kernel<<<(N + 255) / 256, 256, 0, stream>>>(x, Wp, bp, out, N);
}